// Round 3
// baseline (466.267 us; speedup 1.0000x reference)
//
#include <hip/hip_runtime.h>
#include <math.h>

#define NTOT   65536
#define KCODES 1024
#define DDIM   256
#define HWSZ   1024
#define CHW    262144
#define LOSS_OFF 16777216
#define IDX_OFF  16777217

// ---- kernel A: B_k = ||e_k||^2 via numpy-pairwise order; zero loss slot ---
__global__ __launch_bounds__(256) void vq_prep(const float* __restrict__ emb,
                                               float* __restrict__ Bn,
                                               float* __restrict__ loss_slot) {
    int k = blockIdx.x * 256 + threadIdx.x;
    if (k == 0 && blockIdx.x == 0) loss_slot[0] = 0.f;
    if (k < KCODES) {
        const float* e = emb + (size_t)k * DDIM;
        float half[2];
        #pragma unroll
        for (int h = 0; h < 2; ++h) {
            const float* q = e + (h << 7);
            float r[8];
            #pragma unroll
            for (int j = 0; j < 8; ++j) r[j] = __fmul_rn(q[j], q[j]);
            for (int i = 8; i < 128; i += 8) {
                #pragma unroll
                for (int j = 0; j < 8; ++j)
                    r[j] = __fadd_rn(r[j], __fmul_rn(q[i + j], q[i + j]));
            }
            half[h] = __fadd_rn(
                __fadd_rn(__fadd_rn(r[0], r[1]), __fadd_rn(r[2], r[3])),
                __fadd_rn(__fadd_rn(r[4], r[5]), __fadd_rn(r[6], r[7])));
        }
        Bn[k] = __fadd_rn(half[0], half[1]);
    }
}

// ---- kernel A2: A_n = ||z_n||^2 via numpy-pairwise order ------------------
__global__ __launch_bounds__(256) void vq_znorm(const float* __restrict__ z,
                                                float* __restrict__ An) {
    const int blk = blockIdx.x;                 // 256 blocks
    const int b   = blk >> 2;
    const int hw  = ((blk & 3) << 8) + threadIdx.x;
    const float* p = z + (size_t)b * CHW + hw;  // stride HWSZ over c, coalesced over hw
    float half[2];
    #pragma unroll
    for (int h = 0; h < 2; ++h) {
        const float* q = p + (size_t)(h << 7) * HWSZ;
        float r[8];
        #pragma unroll
        for (int j = 0; j < 8; ++j) {
            float v = q[(size_t)j * HWSZ];
            r[j] = __fmul_rn(v, v);
        }
        for (int i = 8; i < 128; i += 8) {
            #pragma unroll
            for (int j = 0; j < 8; ++j) {
                float v = q[(size_t)(i + j) * HWSZ];
                r[j] = __fadd_rn(r[j], __fmul_rn(v, v));
            }
        }
        half[h] = __fadd_rn(
            __fadd_rn(__fadd_rn(r[0], r[1]), __fadd_rn(r[2], r[3])),
            __fadd_rn(__fadd_rn(r[4], r[5]), __fadd_rn(r[6], r[7])));
    }
    An[((size_t)b << 10) + hw] = __fadd_rn(half[0], half[1]);
}

// ---- kernel B: SGEMM + running argmin on reference-bucketed distances -----
__global__ __launch_bounds__(256) void vq_argmin(const float* __restrict__ z,
                                                 const float* __restrict__ emb,
                                                 const float* __restrict__ An,
                                                 const float* __restrict__ Bn,
                                                 float* __restrict__ idx_out) {
    __shared__ float Zs[32][128];
    __shared__ float Es[32][132];
    __shared__ float RV[128][17];
    __shared__ int   RI[128][17];

    const int t  = threadIdx.x;
    const int nb = blockIdx.x;
    const int b   = nb >> 3;
    const int hw0 = (nb & 7) << 7;
    const float* zbase = z + (size_t)b * CHW + hw0;

    const int tn = t & 15;
    const int tk = t >> 4;

    // preload A for this thread's 8 rows (fixed across k-chunks)
    float Arow[8];
    #pragma unroll
    for (int i = 0; i < 8; ++i) {
        int ni = (i < 4) ? ((tn << 2) + i) : (64 + (tn << 2) + (i - 4));
        Arow[i] = An[((size_t)b << 10) + hw0 + ni];
    }

    float mv[8];
    int   mi[8];
    #pragma unroll
    for (int i = 0; i < 8; ++i) { mv[i] = 3.4e38f; mi[i] = 0; }

    for (int k0 = 0; k0 < KCODES; k0 += 128) {
        float acc[8][8];
        #pragma unroll
        for (int i = 0; i < 8; ++i)
            #pragma unroll
            for (int j = 0; j < 8; ++j) acc[i][j] = 0.f;

        for (int c0 = 0; c0 < DDIM; c0 += 32) {
            {
                const int l = t & 31;
                #pragma unroll
                for (int it = 0; it < 4; ++it) {
                    int cc = (t >> 5) + (it << 3);
                    float4 v = *reinterpret_cast<const float4*>(
                        zbase + (size_t)(c0 + cc) * HWSZ + (l << 2));
                    *reinterpret_cast<float4*>(&Zs[cc][l << 2]) = v;
                }
            }
            {
                const int kk = t >> 1;
                const int cg = (t & 1) << 4;
                const float* ebase = emb + (size_t)(k0 + kk) * DDIM + c0 + cg;
                #pragma unroll
                for (int q = 0; q < 4; ++q) {
                    float4 v = *reinterpret_cast<const float4*>(ebase + (q << 2));
                    Es[cg + (q << 2) + 0][kk] = v.x;
                    Es[cg + (q << 2) + 1][kk] = v.y;
                    Es[cg + (q << 2) + 2][kk] = v.z;
                    Es[cg + (q << 2) + 3][kk] = v.w;
                }
            }
            __syncthreads();
            #pragma unroll 8
            for (int dd = 0; dd < 32; ++dd) {
                float4 a0 = *reinterpret_cast<const float4*>(&Zs[dd][tn << 2]);
                float4 a1 = *reinterpret_cast<const float4*>(&Zs[dd][64 + (tn << 2)]);
                float4 b0 = *reinterpret_cast<const float4*>(&Es[dd][tk << 3]);
                float4 b1 = *reinterpret_cast<const float4*>(&Es[dd][(tk << 3) + 4]);
                float a[8]  = {a0.x, a0.y, a0.z, a0.w, a1.x, a1.y, a1.z, a1.w};
                float bb[8] = {b0.x, b0.y, b0.z, b0.w, b1.x, b1.y, b1.z, b1.w};
                #pragma unroll
                for (int i = 0; i < 8; ++i)
                    #pragma unroll
                    for (int j = 0; j < 8; ++j)
                        acc[i][j] = fmaf(a[i], bb[j], acc[i][j]);
            }
            __syncthreads();
        }
        // fold: replicate reference f32 expression tree
        //   s = fl32( fl32(A + B_k) - fl32(2*dot) )   (bucketed at |A|~256)
        #pragma unroll
        for (int i = 0; i < 8; ++i) {
            #pragma unroll
            for (int j = 0; j < 8; ++j) {
                int k = k0 + (tk << 3) + j;
                float t1 = __fadd_rn(Arow[i], Bn[k]);
                float s  = __fsub_rn(t1, __fmul_rn(2.0f, acc[i][j]));
                if (s < mv[i]) { mv[i] = s; mi[i] = k; }
            }
        }
    }

    #pragma unroll
    for (int i = 0; i < 8; ++i) {
        int ni = (i < 4) ? ((tn << 2) + i) : (64 + (tn << 2) + (i - 4));
        RV[ni][tk] = mv[i];
        RI[ni][tk] = mi[i];
    }
    __syncthreads();
    if (t < 128) {
        float bv = RV[t][0];
        int   bi = RI[t][0];
        #pragma unroll
        for (int j = 1; j < 16; ++j) {
            float v = RV[t][j];
            int  ii = RI[t][j];
            if (v < bv || (v == bv && ii < bi)) { bv = v; bi = ii; }
        }
        idx_out[(size_t)nb * 128 + t] = (float)bi;
    }
}

// ---- kernel C: gather codebook rows, write out, loss ----------------------
__global__ __launch_bounds__(256) void vq_epilogue(const float* __restrict__ z,
                                                   const float* __restrict__ emb,
                                                   float* __restrict__ outp,
                                                   const float* __restrict__ idxf,
                                                   float* __restrict__ loss_slot) {
    const int t  = threadIdx.x;
    const int nc = blockIdx.x;
    const int b  = nc >> 4;
    const int hw = ((nc & 15) << 6) + (t & 63);
    const int n  = (b << 10) + hw;
    const int idx = (int)idxf[n];
    const float* erow = emb + (size_t)idx * DDIM;
    const size_t zb = (size_t)b * CHW + hw;

    float accl = 0.f;
    const int cbase = (t >> 6) << 2;
    #pragma unroll 4
    for (int cq = 0; cq < 16; ++cq) {
        int c = cbase + (cq << 4);
        float4 q4 = *reinterpret_cast<const float4*>(erow + c);
        float qv[4] = {q4.x, q4.y, q4.z, q4.w};
        #pragma unroll
        for (int j = 0; j < 4; ++j) {
            size_t a = zb + (size_t)(c + j) * HWSZ;
            float zv = z[a];
            outp[a] = qv[j];
            float d = qv[j] - zv;
            accl = fmaf(d, d, accl);
        }
    }
    #pragma unroll
    for (int off = 32; off > 0; off >>= 1)
        accl += __shfl_down(accl, off, 64);
    __shared__ float r[4];
    if ((t & 63) == 0) r[t >> 6] = accl;
    __syncthreads();
    if (t == 0) {
        float s = (r[0] + r[1]) + (r[2] + r[3]);
        atomicAdd(loss_slot, s * (1.25f / 16777216.f));
    }
}

extern "C" void kernel_launch(void* const* d_in, const int* in_sizes, int n_in,
                              void* d_out, int out_size, void* d_ws, size_t ws_size,
                              hipStream_t stream) {
    const float* z   = (const float*)d_in[0];
    const float* emb = (const float*)d_in[1];
    float* out       = (float*)d_out;
    float* loss_slot = out + LOSS_OFF;
    float* idx_out   = out + IDX_OFF;
    float* Bn        = (float*)d_ws;          // 1024 floats
    float* An        = (float*)d_ws + 1024;   // 65536 floats

    vq_prep    <<<dim3(4),    dim3(256), 0, stream>>>(emb, Bn, loss_slot);
    vq_znorm   <<<dim3(256),  dim3(256), 0, stream>>>(z, An);
    vq_argmin  <<<dim3(512),  dim3(256), 0, stream>>>(z, emb, An, Bn, idx_out);
    vq_epilogue<<<dim3(1024), dim3(256), 0, stream>>>(z, emb, out, idx_out, loss_slot);
}